// Round 1
// baseline (100.069 us; speedup 1.0000x reference)
//
#include <hip/hip_runtime.h>

#define P_TOT 30000
#define NPT   100
#define COUT  64
#define NB1   512

static constexpr float VXf   = 0.16f;
static constexpr float VYf   = 0.16f;
static constexpr float XOFFf = 0.08f;            // VX/2 + 0.0
static constexpr float YOFFf = 0.08f - 39.68f;   // VY/2 + y_min
static constexpr float INV_M = 1.0f / 3000000.0f; // 1/(P*N)

__device__ inline float wred(float v) {
#pragma unroll
  for (int d = 1; d < 64; d <<= 1) v += __shfl_xor(v, d);
  return v;
}

__device__ inline void accum9(float* S1, float* S2, const float4& a,
                              float mx, float my, float mz,
                              float cxc, float cyc) {
  float f[9];
  f[0] = a.x; f[1] = a.y; f[2] = a.z; f[3] = a.w;
  f[4] = a.x - mx; f[5] = a.y - my; f[6] = a.z - mz;
  f[7] = a.x - cxc; f[8] = a.y - cyc;
#pragma unroll
  for (int i = 0; i < 9; i++) S1[i] += f[i];
  int k = 0;
#pragma unroll
  for (int i = 0; i < 9; i++) {
#pragma unroll
    for (int j = i; j < 9; j++) { S2[k] += f[i] * f[j]; k++; }
  }
}

// K1: per-pillar feature moments -> per-block partial sums (deterministic)
__global__ __launch_bounds__(256) void k1_stats(
    const float4* __restrict__ feat, const int* __restrict__ npts,
    const int* __restrict__ coords, float* __restrict__ partials) {
  const int lane = threadIdx.x & 63;
  const int wv   = threadIdx.x >> 6;
  const int wave_id = blockIdx.x * 4 + wv;
  const int nwaves  = gridDim.x * 4;

  float S1[9], S2[45];
#pragma unroll
  for (int i = 0; i < 9; i++) S1[i] = 0.f;
#pragma unroll
  for (int i = 0; i < 45; i++) S2[i] = 0.f;

  for (int p = wave_id; p < P_TOT; p += nwaves) {
    const int np = npts[p];
    const int n0 = lane, n1 = lane + 64;
    float4 a0 = make_float4(0.f, 0.f, 0.f, 0.f), a1 = a0;
    if (n0 < NPT) a0 = feat[p * NPT + n0];
    if (n1 < NPT) a1 = feat[p * NPT + n1];
    // reference sums xyz over ALL N points, divides by num_points
    float sx = wred(a0.x + a1.x);
    float sy = wred(a0.y + a1.y);
    float sz = wred(a0.z + a1.z);
    const float inv = 1.f / (float)np;
    const float mx = sx * inv, my = sy * inv, mz = sz * inv;
    const float cxc = (float)coords[p * 4 + 3] * VXf + XOFFf;
    const float cyc = (float)coords[p * 4 + 2] * VYf + YOFFf;
    if (n0 < np) accum9(S1, S2, a0, mx, my, mz, cxc, cyc);
    if (n1 < np) accum9(S1, S2, a1, mx, my, mz, cxc, cyc);
  }

  __shared__ float red[4][54];
#pragma unroll
  for (int i = 0; i < 9; i++) {
    float v = wred(S1[i]);
    if (lane == 0) red[wv][i] = v;
  }
#pragma unroll
  for (int k = 0; k < 45; k++) {
    float v = wred(S2[k]);
    if (lane == 0) red[wv][9 + k] = v;
  }
  __syncthreads();
  if (threadIdx.x < 54) {
    partials[blockIdx.x * 54 + threadIdx.x] =
        red[0][threadIdx.x] + red[1][threadIdx.x] +
        red[2][threadIdx.x] + red[3][threadIdx.x];
  }
}

// K2: reduce partials, fold BN into linear: W' = W*scale, shift, relu(shift)
__global__ void k2_bn(const float* __restrict__ partials,
                      const float* __restrict__ W,
                      const float* __restrict__ gamma,
                      const float* __restrict__ beta,
                      float* __restrict__ bn) {
  __shared__ float S[54];
  const int t = threadIdx.x;
  if (t < 54) {
    float s = 0.f;
    for (int b = 0; b < NB1; b++) s += partials[b * 54 + t];
    S[t] = s;
  }
  __syncthreads();
  if (t < COUT) {
    float w[9];
#pragma unroll
    for (int i = 0; i < 9; i++) w[i] = W[t * 9 + i];
    float mean = 0.f;
#pragma unroll
    for (int i = 0; i < 9; i++) mean += w[i] * S[i];
    mean *= INV_M;
    float e2 = 0.f;
    int k = 9;
#pragma unroll
    for (int i = 0; i < 9; i++) {
#pragma unroll
      for (int j = i; j < 9; j++) {
        float c = w[i] * w[j] * S[k];
        e2 += (i == j) ? c : 2.f * c;
        k++;
      }
    }
    e2 *= INV_M;
    const float var = e2 - mean * mean;
    const float scale = gamma[t] * rsqrtf(var + 0.001f);
    const float shift = beta[t] - mean * scale;
#pragma unroll
    for (int i = 0; i < 9; i++) bn[t * 9 + i] = w[i] * scale;
    bn[576 + t] = shift;
    bn[640 + t] = fmaxf(shift, 0.f);
  }
}

// K3: wave per pillar, lane = output channel; max over points of relu(f.W'+shift)
__global__ __launch_bounds__(256) void k3_out(
    const float4* __restrict__ feat, const int* __restrict__ npts,
    const int* __restrict__ coords, const float* __restrict__ bn,
    float* __restrict__ out) {
  __shared__ float4 pts[4][NPT];
  const int lane = threadIdx.x & 63;
  const int wv   = threadIdx.x >> 6;
  const int p    = blockIdx.x * 4 + wv;   // grid exact: 7500*4 == 30000

  const int np = npts[p];
  float4 a0 = make_float4(0.f, 0.f, 0.f, 0.f), a1 = a0;
  if (lane < NPT) a0 = feat[p * NPT + lane];
  if (lane + 64 < NPT) a1 = feat[p * NPT + lane + 64];
  float sx = wred(a0.x + a1.x);
  float sy = wred(a0.y + a1.y);
  float sz = wred(a0.z + a1.z);
  const float inv = 1.f / (float)np;
  const float mx = sx * inv, my = sy * inv, mz = sz * inv;
  const float cxc = (float)coords[p * 4 + 3] * VXf + XOFFf;
  const float cyc = (float)coords[p * 4 + 2] * VYf + YOFFf;

  if (lane < NPT) pts[wv][lane] = a0;
  if (lane + 64 < NPT) pts[wv][lane + 64] = a1;

  float w[9];
#pragma unroll
  for (int i = 0; i < 9; i++) w[i] = bn[lane * 9 + i];
  const float shift = bn[576 + lane];
  const float rsh   = bn[640 + lane];

  __syncthreads();

  float m = (np < NPT) ? rsh : 0.f;  // padded positions contribute relu(shift)
  for (int n = 0; n < np; n++) {
    const float4 q = pts[wv][n];
    float acc = shift;
    acc = fmaf(q.x, w[0], acc);
    acc = fmaf(q.y, w[1], acc);
    acc = fmaf(q.z, w[2], acc);
    acc = fmaf(q.w, w[3], acc);
    acc = fmaf(q.x - mx, w[4], acc);
    acc = fmaf(q.y - my, w[5], acc);
    acc = fmaf(q.z - mz, w[6], acc);
    acc = fmaf(q.x - cxc, w[7], acc);
    acc = fmaf(q.y - cyc, w[8], acc);
    m = fmaxf(m, acc);  // relu subsumed: m starts >= 0
  }
  out[p * COUT + lane] = m;
}

extern "C" void kernel_launch(void* const* d_in, const int* in_sizes, int n_in,
                              void* d_out, int out_size, void* d_ws, size_t ws_size,
                              hipStream_t stream) {
  const float4* feat  = (const float4*)d_in[0];
  const int*   npts   = (const int*)d_in[1];
  const int*   coords = (const int*)d_in[2];
  const float* W      = (const float*)d_in[3];
  const float* gamma  = (const float*)d_in[4];
  const float* beta   = (const float*)d_in[5];
  float* out = (float*)d_out;

  float* partials = (float*)d_ws;               // NB1*54 floats
  float* bn       = partials + NB1 * 54;        // 576 + 64 + 64 floats

  k1_stats<<<NB1, 256, 0, stream>>>(feat, npts, coords, partials);
  k2_bn<<<1, 64, 0, stream>>>(partials, W, gamma, beta, bn);
  k3_out<<<P_TOT / 4, 256, 0, stream>>>(feat, npts, coords, bn, out);
}

// Round 2
// 75.077 us; speedup vs baseline: 1.3329x; 1.3329x over previous
//
#include <hip/hip_runtime.h>

#define P_TOT 30000
#define NPT   100
#define COUT  64

static constexpr float VXf   = 0.16f;
static constexpr float VYf   = 0.16f;
static constexpr float XOFFf = 0.08f;            // VX/2 + 0.0
static constexpr float YOFFf = 0.08f - 39.68f;   // VY/2 + y_min
static constexpr float INV_M = 1.0f / 3000000.0f; // 1/(P*N)

__device__ inline float wred(float v) {
#pragma unroll
  for (int d = 1; d < 64; d <<= 1) v += __shfl_xor(v, d);
  return v;
}

__device__ inline void accum9(float* S1, float* S2, const float4& a,
                              float mx, float my, float mz,
                              float cxc, float cyc) {
  float f[9];
  f[0] = a.x; f[1] = a.y; f[2] = a.z; f[3] = a.w;
  f[4] = a.x - mx; f[5] = a.y - my; f[6] = a.z - mz;
  f[7] = a.x - cxc; f[8] = a.y - cyc;
#pragma unroll
  for (int i = 0; i < 9; i++) S1[i] += f[i];
  int k = 0;
#pragma unroll
  for (int i = 0; i < 9; i++) {
#pragma unroll
    for (int j = i; j < 9; j++) { S2[k] += f[i] * f[j]; k++; }
  }
}

// K1: per-pillar feature moments -> per-block partials, moment-major layout
__global__ __launch_bounds__(256) void k1_stats(
    const float4* __restrict__ feat, const int* __restrict__ npts,
    const int* __restrict__ coords, float* __restrict__ partials, int nb1) {
  const int lane = threadIdx.x & 63;
  const int wv   = threadIdx.x >> 6;
  const int wave_id = blockIdx.x * 4 + wv;
  const int nwaves  = nb1 * 4;

  float S1[9], S2[45];
#pragma unroll
  for (int i = 0; i < 9; i++) S1[i] = 0.f;
#pragma unroll
  for (int i = 0; i < 45; i++) S2[i] = 0.f;

  for (int p = wave_id; p < P_TOT; p += nwaves) {
    const int np = npts[p];
    float4 a0 = make_float4(0.f, 0.f, 0.f, 0.f), a1 = a0;
    if (lane < NPT) a0 = feat[p * NPT + lane];
    if (lane + 64 < NPT) a1 = feat[p * NPT + lane + 64];
    // reference sums xyz over ALL N points, divides by num_points
    float sx = wred(a0.x + a1.x);
    float sy = wred(a0.y + a1.y);
    float sz = wred(a0.z + a1.z);
    const float inv = 1.f / (float)np;
    const float mx = sx * inv, my = sy * inv, mz = sz * inv;
    const float cxc = (float)coords[p * 4 + 3] * VXf + XOFFf;
    const float cyc = (float)coords[p * 4 + 2] * VYf + YOFFf;
    if (lane < np) accum9(S1, S2, a0, mx, my, mz, cxc, cyc);
    if (lane + 64 < np) accum9(S1, S2, a1, mx, my, mz, cxc, cyc);
  }

  __shared__ float red[4][54];
#pragma unroll
  for (int i = 0; i < 9; i++) {
    float v = wred(S1[i]);
    if (lane == 0) red[wv][i] = v;
  }
#pragma unroll
  for (int k = 0; k < 45; k++) {
    float v = wred(S2[k]);
    if (lane == 0) red[wv][9 + k] = v;
  }
  __syncthreads();
  if (threadIdx.x < 54) {
    partials[threadIdx.x * nb1 + blockIdx.x] =
        red[0][threadIdx.x] + red[1][threadIdx.x] +
        red[2][threadIdx.x] + red[3][threadIdx.x];
  }
}

// K2: parallel reduce partials (16 waves), fold BN + affine collapse:
//   ce  = (wb0+wb4+wb7, wb1+wb5+wb8, wb2+wb6, wb3)
//   gA  = (wb4, wb5, wb6, shift)
//   gB  = (wb7, wb8, 0, relu(shift))
__global__ __launch_bounds__(1024) void k2_bn(
    const float* __restrict__ partials, int nb1,
    const float* __restrict__ W,
    const float* __restrict__ gamma,
    const float* __restrict__ beta,
    float4* __restrict__ bn) {
  __shared__ float S[54];
  const int lane = threadIdx.x & 63;
  const int wv   = threadIdx.x >> 6;   // 16 waves
  for (int m = wv; m < 54; m += 16) {
    float s = 0.f;
    for (int b = lane; b < nb1; b += 64) s += partials[m * nb1 + b];
    s = wred(s);
    if (lane == 0) S[m] = s;
  }
  __syncthreads();
  const int t = threadIdx.x;
  if (t < COUT) {
    float w[9];
#pragma unroll
    for (int i = 0; i < 9; i++) w[i] = W[t * 9 + i];
    float mean = 0.f;
#pragma unroll
    for (int i = 0; i < 9; i++) mean += w[i] * S[i];
    mean *= INV_M;
    float e2 = 0.f;
    int k = 9;
#pragma unroll
    for (int i = 0; i < 9; i++) {
#pragma unroll
      for (int j = i; j < 9; j++) {
        float c = w[i] * w[j] * S[k];
        e2 += (i == j) ? c : 2.f * c;
        k++;
      }
    }
    e2 *= INV_M;
    const float var = e2 - mean * mean;
    const float scale = gamma[t] * rsqrtf(var + 0.001f);
    const float shift = beta[t] - mean * scale;
    float wb[9];
#pragma unroll
    for (int i = 0; i < 9; i++) wb[i] = w[i] * scale;
    bn[t]        = make_float4(wb[0] + wb[4] + wb[7], wb[1] + wb[5] + wb[8],
                               wb[2] + wb[6], wb[3]);
    bn[64 + t]   = make_float4(wb[4], wb[5], wb[6], shift);
    bn[128 + t]  = make_float4(wb[7], wb[8], 0.f, fmaxf(shift, 0.f));
  }
}

// K3: 1 wave = 1 pillar; lane = channel; 4 FMA + 1 fmax per point
__global__ __launch_bounds__(64) void k3_out(
    const float4* __restrict__ feat, const int* __restrict__ npts,
    const int* __restrict__ coords, const float4* __restrict__ bn,
    float* __restrict__ out) {
  __shared__ float4 pts[NPT];
  const int lane = threadIdx.x;
  const int p    = blockIdx.x;

  const int np = npts[p];
  const float4* fp = feat + p * NPT;
  float4 a0 = make_float4(0.f, 0.f, 0.f, 0.f), a1 = a0;
  if (lane < NPT)      { a0 = fp[lane];      pts[lane] = a0; }
  if (lane + 64 < NPT) { a1 = fp[lane + 64]; pts[lane + 64] = a1; }

  float sx = wred(a0.x + a1.x);
  float sy = wred(a0.y + a1.y);
  float sz = wred(a0.z + a1.z);
  const float inv = 1.f / (float)np;
  const float mx = sx * inv, my = sy * inv, mz = sz * inv;
  const float cxc = (float)coords[p * 4 + 3] * VXf + XOFFf;
  const float cyc = (float)coords[p * 4 + 2] * VYf + YOFFf;

  const float4 ce = bn[lane];
  const float4 gA = bn[64 + lane];
  const float4 gB = bn[128 + lane];
  float bias = gA.w;
  bias = fmaf(-gA.x, mx, bias);
  bias = fmaf(-gA.y, my, bias);
  bias = fmaf(-gA.z, mz, bias);
  bias = fmaf(-gB.x, cxc, bias);
  bias = fmaf(-gB.y, cyc, bias);

  __syncthreads();

  // padded positions contribute relu(shift) when np < N
  float m0 = (np < NPT) ? gB.w : 0.f;
  float m1 = m0;
  int n = 0;
  for (; n + 1 < np; n += 2) {
    const float4 q0 = pts[n];
    const float4 q1 = pts[n + 1];
    float acc0 = bias, acc1 = bias;
    acc0 = fmaf(q0.x, ce.x, acc0);
    acc1 = fmaf(q1.x, ce.x, acc1);
    acc0 = fmaf(q0.y, ce.y, acc0);
    acc1 = fmaf(q1.y, ce.y, acc1);
    acc0 = fmaf(q0.z, ce.z, acc0);
    acc1 = fmaf(q1.z, ce.z, acc1);
    acc0 = fmaf(q0.w, ce.w, acc0);
    acc1 = fmaf(q1.w, ce.w, acc1);
    m0 = fmaxf(m0, acc0);
    m1 = fmaxf(m1, acc1);
  }
  if (n < np) {
    const float4 q = pts[n];
    float acc = bias;
    acc = fmaf(q.x, ce.x, acc);
    acc = fmaf(q.y, ce.y, acc);
    acc = fmaf(q.z, ce.z, acc);
    acc = fmaf(q.w, ce.w, acc);
    m0 = fmaxf(m0, acc);
  }
  out[p * COUT + lane] = fmaxf(m0, m1);
}

extern "C" void kernel_launch(void* const* d_in, const int* in_sizes, int n_in,
                              void* d_out, int out_size, void* d_ws, size_t ws_size,
                              hipStream_t stream) {
  const float4* feat  = (const float4*)d_in[0];
  const int*   npts   = (const int*)d_in[1];
  const int*   coords = (const int*)d_in[2];
  const float* W      = (const float*)d_in[3];
  const float* gamma  = (const float*)d_in[4];
  const float* beta   = (const float*)d_in[5];
  float* out = (float*)d_out;

  // choose K1 block count by available workspace
  const int nb1 = (ws_size >= (size_t)(54 * 1024 * 4 + 192 * 16 + 64)) ? 1024 : 512;
  float*  partials = (float*)d_ws;                 // 54*nb1 floats
  float4* bn       = (float4*)(partials + 54 * nb1); // 192 float4

  k1_stats<<<nb1, 256, 0, stream>>>(feat, npts, coords, partials, nb1);
  k2_bn<<<1, 1024, 0, stream>>>(partials, nb1, W, gamma, beta, bn);
  k3_out<<<P_TOT, 64, 0, stream>>>(feat, npts, coords, bn, out);
}